// Round 6
// baseline (521.542 us; speedup 1.0000x reference)
//
#include <hip/hip_runtime.h>
#include <hip/hip_bf16.h>
#include <math.h>

typedef __hip_bfloat16 bf16;
static __device__ __forceinline__ float b2f(bf16 v) { return __bfloat162float(v); }

constexpr int NN = 200000;   // nodes
constexpr int NE = 600000;   // edges
constexpr int NG = 512;      // graphs

// ---------------- degree ----------------
__global__ void k_deg(const int* __restrict__ dst, float* __restrict__ deg) {
    int e = blockIdx.x * blockDim.x + threadIdx.x;
    if (e < NE) atomicAdd(&deg[dst[e]], 1.0f);
}

// counts[g] via binary search on the SORTED batch array (no atomics)
__global__ void k_countsb(const int* __restrict__ batch, float* __restrict__ counts) {
    int g = blockIdx.x * blockDim.x + threadIdx.x;
    if (g >= NG) return;
    int lo = 0, hi = NN;
    while (lo < hi) { int m = (lo + hi) >> 1; if (batch[m] < g) lo = m + 1; else hi = m; }
    int first = lo;
    lo = 0; hi = NN;
    while (lo < hi) { int m = (lo + hi) >> 1; if (batch[m] < g + 1) lo = m + 1; else hi = m; }
    counts[g] = (float)(lo - first);
}

__global__ void k_dis(float* __restrict__ deg) {
    int n = blockIdx.x * blockDim.x + threadIdx.x;
    if (n < NN) deg[n] = rsqrtf(deg[n] + 1.0f);   // +1 self-loop
}

// ---------------- edge scatter of raw x (2 channels): xa[d] += x[s]*w ----------------
__global__ void k_edgex(const int* __restrict__ ei, const float* __restrict__ dis,
                        const float* __restrict__ x, float* __restrict__ xa) {
    int e = blockIdx.x * blockDim.x + threadIdx.x;
    if (e >= NE) return;
    int s = ei[e], d = ei[NE + e];
    float w = dis[s] * dis[d];
    atomicAdd(&xa[d * 2 + 0], x[s * 2 + 0] * w);
    atomicAdd(&xa[d * 2 + 1], x[s * 2 + 1] * w);
}

// ---------------- layer1 finalize: v = relu((xa + x*dis^2)@W1 + b1)
//  writes h1 (bf16, gather source for edgeh) AND agg = v*dis^2 (fp32, self-loop
//  term pre-folded so no memset + no h1 re-read later) ----------------
__global__ void k_h1(const float* __restrict__ x, const float* __restrict__ xa,
                     const float* __restrict__ dis, const float* __restrict__ W1,
                     const float* __restrict__ b1, bf16* __restrict__ h1,
                     float* __restrict__ agg) {
    int t = blockIdx.x * blockDim.x + threadIdx.x;
    if (t >= NN * 64) return;
    int n = t >> 6, k = t & 63;
    float dd = dis[n]; dd *= dd;
    float a0 = xa[n * 2 + 0] + x[n * 2 + 0] * dd;
    float a1 = xa[n * 2 + 1] + x[n * 2 + 1] * dd;
    float v = fmaxf(a0 * W1[k] + a1 * W1[64 + k] + b1[k], 0.0f);
    h1[t] = __float2bfloat16(v);
    agg[t] = v * dd;
}

// ---------------- edge scatter of h1 (64 channels): agg[d] += h1[s]*w ----------------
__global__ void k_edgeh(const int* __restrict__ ei, const float* __restrict__ dis,
                        const bf16* __restrict__ h1, float* __restrict__ agg) {
    int t = blockIdx.x * blockDim.x + threadIdx.x;
    if (t >= NE * 64) return;
    int e = t >> 6, k = t & 63;
    int s = ei[e], d = ei[NE + e];
    float w = dis[s] * dis[d];
    atomicAdd(&agg[d * 64 + k], b2f(h1[s * 64 + k]) * w);
}

// ---------------- fused: h2=relu(agg@W2+b2); segment-reduced pool ----------------
// block = 256 = 4 waves; wave = 16-node strip x 128 cols.
// lane owns cols (lane, 64+lane): 32 register accumulators, static-indexed
// (fully unrolled) so they CANNOT be demoted. Per j: 2 coalesced W2 loads +
// 16 independent uniform agg loads + 32 independent FMAs -> ILP, not a chain.
// Pool flushed per graph-segment (batch sorted): ~6.4 MB of atomics total.
__global__ void k_l2pool(const float* __restrict__ agg, const float* __restrict__ W2,
                         const float* __restrict__ b2, const int* __restrict__ batch,
                         float* __restrict__ pooled) {
    int lane = threadIdx.x & 63;
    int wid = threadIdx.x >> 6;
    int nbase = blockIdx.x * 64 + wid * 16;

    float acc0[16], acc1[16];
#pragma unroll
    for (int n = 0; n < 16; n++) { acc0[n] = 0.0f; acc1[n] = 0.0f; }

#pragma unroll 2
    for (int j = 0; j < 64; j++) {
        float wv0 = W2[j * 128 + lane];
        float wv1 = W2[j * 128 + 64 + lane];
        const float* __restrict__ col = agg + (size_t)nbase * 64 + j;
#pragma unroll
        for (int n = 0; n < 16; n++) {
            float a = col[n * 64];
            acc0[n] = fmaf(a, wv0, acc0[n]);
            acc1[n] = fmaf(a, wv1, acc1[n]);
        }
    }

    float b2c0 = b2[lane], b2c1 = b2[64 + lane];
    int cur = batch[nbase];
    float s0 = 0.0f, s1 = 0.0f;
#pragma unroll
    for (int n = 0; n < 16; n++) {
        int g = batch[nbase + n];          // wave-uniform branch (batch sorted)
        if (g != cur) {
            atomicAdd(&pooled[cur * 128 + lane], s0);
            atomicAdd(&pooled[cur * 128 + 64 + lane], s1);
            s0 = 0.0f; s1 = 0.0f; cur = g;
        }
        s0 += fmaxf(acc0[n] + b2c0, 0.0f);
        s1 += fmaxf(acc1[n] + b2c1, 0.0f);
    }
    atomicAdd(&pooled[cur * 128 + lane], s0);
    atomicAdd(&pooled[cur * 128 + 64 + lane], s1);
}

// ---------------- fused head: feat MLP + fusion MLP + sigmoid, block per graph ----------------
__global__ void k_head(const float* __restrict__ feat,
                       const float* __restrict__ fW1, const float* __restrict__ fb1,
                       const float* __restrict__ fg1, const float* __restrict__ fbe1,
                       const float* __restrict__ frm1, const float* __restrict__ frv1,
                       const float* __restrict__ fW2, const float* __restrict__ fb2,
                       const float* __restrict__ uW1, const float* __restrict__ ub1,
                       const float* __restrict__ ug1, const float* __restrict__ ube1,
                       const float* __restrict__ urm1, const float* __restrict__ urv1,
                       const float* __restrict__ uW2, const float* __restrict__ ub2,
                       const float* __restrict__ ug2, const float* __restrict__ ube2,
                       const float* __restrict__ urm2, const float* __restrict__ urv2,
                       const float* __restrict__ uW3, const float* __restrict__ ub3,
                       const float* __restrict__ pooled, const float* __restrict__ counts,
                       float* __restrict__ out) {
    int g = blockIdx.x;
    int tid = threadIdx.x;
    __shared__ float t1[256], c[256], d1[192], d2[128];

    float f[8];
#pragma unroll
    for (int i = 0; i < 8; i++) f[i] = feat[g * 8 + i];

    // feat MLP layer 1: 8 -> 256, BN, ReLU
    {
        int j = tid;
        float acc = fb1[j];
#pragma unroll
        for (int i = 0; i < 8; i++) acc += f[i] * fW1[i * 256 + j];
        acc = (acc - frm1[j]) * rsqrtf(frv1[j] + 1e-5f) * fg1[j] + fbe1[j];
        t1[j] = fmaxf(acc, 0.0f);
    }
    __syncthreads();

    // feat MLP layer 2 (256->128) into c[128..255]; pooled mean into c[0..127]
    if (tid < 128) {
        float acc = fb2[tid];
        for (int j = 0; j < 256; j++) acc += t1[j] * fW2[j * 128 + tid];
        c[128 + tid] = acc;
    } else {
        int k = tid - 128;
        float cnt = fmaxf(counts[g], 1.0f);
        c[k] = pooled[g * 128 + k] / cnt;
    }
    __syncthreads();

    // fusion layer 1: 256 -> 192, BN, ReLU
    if (tid < 192) {
        float acc = ub1[tid];
        for (int i = 0; i < 256; i++) acc += c[i] * uW1[i * 192 + tid];
        acc = (acc - urm1[tid]) * rsqrtf(urv1[tid] + 1e-5f) * ug1[tid] + ube1[tid];
        d1[tid] = fmaxf(acc, 0.0f);
    }
    __syncthreads();

    // fusion layer 2: 192 -> 128, BN, ReLU
    if (tid < 128) {
        float acc = ub2[tid];
        for (int i = 0; i < 192; i++) acc += d1[i] * uW2[i * 128 + tid];
        acc = (acc - urm2[tid]) * rsqrtf(urv2[tid] + 1e-5f) * ug2[tid] + ube2[tid];
        d2[tid] = fmaxf(acc, 0.0f);
    }
    __syncthreads();

    // fusion layer 3: 128 -> 1, sigmoid
    if (tid == 0) {
        float s = ub3[0];
        for (int i = 0; i < 128; i++) s += d2[i] * uW3[i];
        out[g] = 1.0f / (1.0f + expf(-s));
    }
}

extern "C" void kernel_launch(void* const* d_in, const int* in_sizes, int n_in,
                              void* d_out, int out_size, void* d_ws, size_t ws_size,
                              hipStream_t stream) {
    const float* x    = (const float*)d_in[0];
    const float* feat = (const float*)d_in[1];
    const float* W1   = (const float*)d_in[2];
    const float* b1   = (const float*)d_in[3];
    const float* W2   = (const float*)d_in[4];
    const float* b2   = (const float*)d_in[5];
    const float* fW1  = (const float*)d_in[6];
    const float* fb1  = (const float*)d_in[7];
    const float* fg1  = (const float*)d_in[8];
    const float* fbe1 = (const float*)d_in[9];
    const float* frm1 = (const float*)d_in[10];
    const float* frv1 = (const float*)d_in[11];
    const float* fW2  = (const float*)d_in[12];
    const float* fb2  = (const float*)d_in[13];
    const float* uW1  = (const float*)d_in[14];
    const float* ub1  = (const float*)d_in[15];
    const float* ug1  = (const float*)d_in[16];
    const float* ube1 = (const float*)d_in[17];
    const float* urm1 = (const float*)d_in[18];
    const float* urv1 = (const float*)d_in[19];
    const float* uW2  = (const float*)d_in[20];
    const float* ub2  = (const float*)d_in[21];
    const float* ug2  = (const float*)d_in[22];
    const float* ube2 = (const float*)d_in[23];
    const float* urm2 = (const float*)d_in[24];
    const float* urv2 = (const float*)d_in[25];
    const float* uW3  = (const float*)d_in[26];
    const float* ub3  = (const float*)d_in[27];
    const int* ei    = (const int*)d_in[28];   // [2, E]
    const int* batch = (const int*)d_in[29];   // [N]
    float* out = (float*)d_out;

    // workspace layout — total ~80 MB
    char* p = (char*)d_ws;
    float* dis    = (float*)p; p += (size_t)NN * 4;            // deg -> dis in place
    float* xa     = (float*)p; p += (size_t)NN * 2 * 4;        // aggregated x
    float* agg    = (float*)p; p += (size_t)NN * 64 * 4;       // self-loop + aggregated h1
    bf16*  h1     = (bf16*)p;  p += (size_t)NN * 64 * 2;       // relu'd layer-1 output
    float* counts = (float*)p; p += (size_t)NG * 4;
    float* pooled = (float*)p; p += (size_t)NG * 128 * 4;

    hipMemsetAsync(dis,    0, (size_t)NN * 4, stream);
    hipMemsetAsync(xa,     0, (size_t)NN * 2 * 4, stream);
    hipMemsetAsync(pooled, 0, (size_t)NG * 128 * 4, stream);

    k_deg<<<(NE + 255) / 256, 256, 0, stream>>>(ei + NE, dis);
    k_countsb<<<(NG + 255) / 256, 256, 0, stream>>>(batch, counts);
    k_dis<<<(NN + 255) / 256, 256, 0, stream>>>(dis);

    // GCN layer 1: aggregate x first (2 channels), then W1+bias+relu (agg pre-filled)
    k_edgex<<<(NE + 255) / 256, 256, 0, stream>>>(ei, dis, x, xa);
    k_h1<<<(NN * 64 + 255) / 256, 256, 0, stream>>>(x, xa, dis, W1, b1, h1, agg);

    // GCN layer 2: aggregate h1 (64 channels), then fused W2+bias+relu+segment-pool
    k_edgeh<<<(NE * 64 + 255) / 256, 256, 0, stream>>>(ei, dis, h1, agg);
    k_l2pool<<<NN / 64, 256, 0, stream>>>(agg, W2, b2, batch, pooled);

    // fused MLP head
    k_head<<<NG, 256, 0, stream>>>(feat, fW1, fb1, fg1, fbe1, frm1, frv1, fW2, fb2,
                                   uW1, ub1, ug1, ube1, urm1, urv1,
                                   uW2, ub2, ug2, ube2, urm2, urv2, uW3, ub3,
                                   pooled, counts, out);
}

// Round 7
// 368.759 us; speedup vs baseline: 1.4143x; 1.4143x over previous
//
#include <hip/hip_runtime.h>
#include <hip/hip_bf16.h>
#include <math.h>

typedef __hip_bfloat16 bf16;
static __device__ __forceinline__ float b2f(bf16 v) { return __bfloat162float(v); }

constexpr int NN = 200000;   // nodes
constexpr int NE = 600000;   // edges
constexpr int NG = 512;      // graphs

// ---------------- degree ----------------
__global__ void k_deg(const int* __restrict__ dst, float* __restrict__ deg) {
    int e = blockIdx.x * blockDim.x + threadIdx.x;
    if (e < NE) atomicAdd(&deg[dst[e]], 1.0f);
}

// counts[g] via binary search on the SORTED batch array (no atomics)
__global__ void k_countsb(const int* __restrict__ batch, float* __restrict__ counts) {
    int g = blockIdx.x * blockDim.x + threadIdx.x;
    if (g >= NG) return;
    int lo = 0, hi = NN;
    while (lo < hi) { int m = (lo + hi) >> 1; if (batch[m] < g) lo = m + 1; else hi = m; }
    int first = lo;
    lo = 0; hi = NN;
    while (lo < hi) { int m = (lo + hi) >> 1; if (batch[m] < g + 1) lo = m + 1; else hi = m; }
    counts[g] = (float)(lo - first);
}

__global__ void k_dis(float* __restrict__ deg) {
    int n = blockIdx.x * blockDim.x + threadIdx.x;
    if (n < NN) deg[n] = rsqrtf(deg[n] + 1.0f);   // +1 self-loop
}

// ---------------- edge scatter of raw x (2 channels): xa[d] += x[s]*w ----------------
__global__ void k_edgex(const int* __restrict__ ei, const float* __restrict__ dis,
                        const float* __restrict__ x, float* __restrict__ xa) {
    int e = blockIdx.x * blockDim.x + threadIdx.x;
    if (e >= NE) return;
    int s = ei[e], d = ei[NE + e];
    float w = dis[s] * dis[d];
    atomicAdd(&xa[d * 2 + 0], x[s * 2 + 0] * w);
    atomicAdd(&xa[d * 2 + 1], x[s * 2 + 1] * w);
}

// ---------------- layer1 finalize: v = relu((xa + x*dis^2)@W1 + b1)
//  writes h1 (bf16, gather source for edgeh) AND agg = v*dis^2 (fp32, self-loop
//  term pre-folded so no memset + no h1 re-read later) ----------------
__global__ void k_h1(const float* __restrict__ x, const float* __restrict__ xa,
                     const float* __restrict__ dis, const float* __restrict__ W1,
                     const float* __restrict__ b1, bf16* __restrict__ h1,
                     float* __restrict__ agg) {
    int t = blockIdx.x * blockDim.x + threadIdx.x;
    if (t >= NN * 64) return;
    int n = t >> 6, k = t & 63;
    float dd = dis[n]; dd *= dd;
    float a0 = xa[n * 2 + 0] + x[n * 2 + 0] * dd;
    float a1 = xa[n * 2 + 1] + x[n * 2 + 1] * dd;
    float v = fmaxf(a0 * W1[k] + a1 * W1[64 + k] + b1[k], 0.0f);
    h1[t] = __float2bfloat16(v);
    agg[t] = v * dd;
}

// ---------------- edge scatter of h1 (64 channels): agg[d] += h1[s]*w ----------------
__global__ void k_edgeh(const int* __restrict__ ei, const float* __restrict__ dis,
                        const bf16* __restrict__ h1, float* __restrict__ agg) {
    int t = blockIdx.x * blockDim.x + threadIdx.x;
    if (t >= NE * 64) return;
    int e = t >> 6, k = t & 63;
    int s = ei[e], d = ei[NE + e];
    float w = dis[s] * dis[d];
    atomicAdd(&agg[d * 64 + k], b2f(h1[s * 64 + k]) * w);
}

// ---------------- fused: h2=relu(agg@W2+b2); segment-reduced pool ----------------
// Round-6 lesson: wave-uniform GLOBAL loads serialize (219us, VALU 19%).
// Fix: stage 64-node agg tile in LDS via coalesced float4 (global is streamed
// exactly once, coalesced); inner loop reads gs via broadcast ds_read_b128
// (uniform address -> conflict-free) + 8 coalesced L1-hot W2 loads per j-step;
// 32 register accumulators, static-indexed. Segment-pool epilogue unchanged
// (proven: 6.5 MB atomic writes).
constexpr int BN = 64;
__global__ __launch_bounds__(256) void k_l2pool(const float* __restrict__ agg,
                         const float* __restrict__ W2, const float* __restrict__ b2,
                         const int* __restrict__ batch, float* __restrict__ pooled) {
    __shared__ float gs[BN * 64];       // 16 KB
    int tid = threadIdx.x;

    // stage: 64 rows x 64 floats = 1024 float4, 4 per thread, coalesced
    {
        const float4* __restrict__ src = (const float4*)(agg + (size_t)blockIdx.x * BN * 64);
        float4* dst = (float4*)gs;
#pragma unroll
        for (int k = 0; k < 4; k++) dst[tid + k * 256] = src[tid + k * 256];
    }
    __syncthreads();

    int lane = tid & 63;
    int wid = tid >> 6;
    int nb = wid * 16;                       // local node base (wave strip)
    int gnb = blockIdx.x * BN + nb;          // global node base

    float acc0[16], acc1[16];
#pragma unroll
    for (int n = 0; n < 16; n++) { acc0[n] = 0.0f; acc1[n] = 0.0f; }

    for (int j = 0; j < 64; j += 4) {
        float w00 = W2[(j + 0) * 128 + lane], w01 = W2[(j + 0) * 128 + 64 + lane];
        float w10 = W2[(j + 1) * 128 + lane], w11 = W2[(j + 1) * 128 + 64 + lane];
        float w20 = W2[(j + 2) * 128 + lane], w21 = W2[(j + 2) * 128 + 64 + lane];
        float w30 = W2[(j + 3) * 128 + lane], w31 = W2[(j + 3) * 128 + 64 + lane];
#pragma unroll
        for (int n = 0; n < 16; n++) {
            float4 g = *(const float4*)&gs[(nb + n) * 64 + j];   // broadcast b128
            acc0[n] = fmaf(g.x, w00, acc0[n]);
            acc1[n] = fmaf(g.x, w01, acc1[n]);
            acc0[n] = fmaf(g.y, w10, acc0[n]);
            acc1[n] = fmaf(g.y, w11, acc1[n]);
            acc0[n] = fmaf(g.z, w20, acc0[n]);
            acc1[n] = fmaf(g.z, w21, acc1[n]);
            acc0[n] = fmaf(g.w, w30, acc0[n]);
            acc1[n] = fmaf(g.w, w31, acc1[n]);
        }
    }

    float b2c0 = b2[lane], b2c1 = b2[64 + lane];
    int cur = batch[gnb];
    float s0 = 0.0f, s1 = 0.0f;
#pragma unroll
    for (int n = 0; n < 16; n++) {
        int g = batch[gnb + n];              // wave-uniform branch (batch sorted)
        if (g != cur) {
            atomicAdd(&pooled[cur * 128 + lane], s0);
            atomicAdd(&pooled[cur * 128 + 64 + lane], s1);
            s0 = 0.0f; s1 = 0.0f; cur = g;
        }
        s0 += fmaxf(acc0[n] + b2c0, 0.0f);
        s1 += fmaxf(acc1[n] + b2c1, 0.0f);
    }
    atomicAdd(&pooled[cur * 128 + lane], s0);
    atomicAdd(&pooled[cur * 128 + 64 + lane], s1);
}

// ---------------- fused head: feat MLP + fusion MLP + sigmoid, block per graph ----------------
__global__ void k_head(const float* __restrict__ feat,
                       const float* __restrict__ fW1, const float* __restrict__ fb1,
                       const float* __restrict__ fg1, const float* __restrict__ fbe1,
                       const float* __restrict__ frm1, const float* __restrict__ frv1,
                       const float* __restrict__ fW2, const float* __restrict__ fb2,
                       const float* __restrict__ uW1, const float* __restrict__ ub1,
                       const float* __restrict__ ug1, const float* __restrict__ ube1,
                       const float* __restrict__ urm1, const float* __restrict__ urv1,
                       const float* __restrict__ uW2, const float* __restrict__ ub2,
                       const float* __restrict__ ug2, const float* __restrict__ ube2,
                       const float* __restrict__ urm2, const float* __restrict__ urv2,
                       const float* __restrict__ uW3, const float* __restrict__ ub3,
                       const float* __restrict__ pooled, const float* __restrict__ counts,
                       float* __restrict__ out) {
    int g = blockIdx.x;
    int tid = threadIdx.x;
    __shared__ float t1[256], c[256], d1[192], d2[128];

    float f[8];
#pragma unroll
    for (int i = 0; i < 8; i++) f[i] = feat[g * 8 + i];

    // feat MLP layer 1: 8 -> 256, BN, ReLU
    {
        int j = tid;
        float acc = fb1[j];
#pragma unroll
        for (int i = 0; i < 8; i++) acc += f[i] * fW1[i * 256 + j];
        acc = (acc - frm1[j]) * rsqrtf(frv1[j] + 1e-5f) * fg1[j] + fbe1[j];
        t1[j] = fmaxf(acc, 0.0f);
    }
    __syncthreads();

    // feat MLP layer 2 (256->128) into c[128..255]; pooled mean into c[0..127]
    if (tid < 128) {
        float acc = fb2[tid];
        for (int j = 0; j < 256; j++) acc += t1[j] * fW2[j * 128 + tid];
        c[128 + tid] = acc;
    } else {
        int k = tid - 128;
        float cnt = fmaxf(counts[g], 1.0f);
        c[k] = pooled[g * 128 + k] / cnt;
    }
    __syncthreads();

    // fusion layer 1: 256 -> 192, BN, ReLU
    if (tid < 192) {
        float acc = ub1[tid];
        for (int i = 0; i < 256; i++) acc += c[i] * uW1[i * 192 + tid];
        acc = (acc - urm1[tid]) * rsqrtf(urv1[tid] + 1e-5f) * ug1[tid] + ube1[tid];
        d1[tid] = fmaxf(acc, 0.0f);
    }
    __syncthreads();

    // fusion layer 2: 192 -> 128, BN, ReLU
    if (tid < 128) {
        float acc = ub2[tid];
        for (int i = 0; i < 192; i++) acc += d1[i] * uW2[i * 128 + tid];
        acc = (acc - urm2[tid]) * rsqrtf(urv2[tid] + 1e-5f) * ug2[tid] + ube2[tid];
        d2[tid] = fmaxf(acc, 0.0f);
    }
    __syncthreads();

    // fusion layer 3: 128 -> 1, sigmoid
    if (tid == 0) {
        float s = ub3[0];
        for (int i = 0; i < 128; i++) s += d2[i] * uW3[i];
        out[g] = 1.0f / (1.0f + expf(-s));
    }
}

extern "C" void kernel_launch(void* const* d_in, const int* in_sizes, int n_in,
                              void* d_out, int out_size, void* d_ws, size_t ws_size,
                              hipStream_t stream) {
    const float* x    = (const float*)d_in[0];
    const float* feat = (const float*)d_in[1];
    const float* W1   = (const float*)d_in[2];
    const float* b1   = (const float*)d_in[3];
    const float* W2   = (const float*)d_in[4];
    const float* b2   = (const float*)d_in[5];
    const float* fW1  = (const float*)d_in[6];
    const float* fb1  = (const float*)d_in[7];
    const float* fg1  = (const float*)d_in[8];
    const float* fbe1 = (const float*)d_in[9];
    const float* frm1 = (const float*)d_in[10];
    const float* frv1 = (const float*)d_in[11];
    const float* fW2  = (const float*)d_in[12];
    const float* fb2  = (const float*)d_in[13];
    const float* uW1  = (const float*)d_in[14];
    const float* ub1  = (const float*)d_in[15];
    const float* ug1  = (const float*)d_in[16];
    const float* ube1 = (const float*)d_in[17];
    const float* urm1 = (const float*)d_in[18];
    const float* urv1 = (const float*)d_in[19];
    const float* uW2  = (const float*)d_in[20];
    const float* ub2  = (const float*)d_in[21];
    const float* ug2  = (const float*)d_in[22];
    const float* ube2 = (const float*)d_in[23];
    const float* urm2 = (const float*)d_in[24];
    const float* urv2 = (const float*)d_in[25];
    const float* uW3  = (const float*)d_in[26];
    const float* ub3  = (const float*)d_in[27];
    const int* ei    = (const int*)d_in[28];   // [2, E]
    const int* batch = (const int*)d_in[29];   // [N]
    float* out = (float*)d_out;

    // workspace layout — total ~80 MB
    char* p = (char*)d_ws;
    float* dis    = (float*)p; p += (size_t)NN * 4;            // deg -> dis in place
    float* xa     = (float*)p; p += (size_t)NN * 2 * 4;        // aggregated x
    float* agg    = (float*)p; p += (size_t)NN * 64 * 4;       // self-loop + aggregated h1
    bf16*  h1     = (bf16*)p;  p += (size_t)NN * 64 * 2;       // relu'd layer-1 output
    float* counts = (float*)p; p += (size_t)NG * 4;
    float* pooled = (float*)p; p += (size_t)NG * 128 * 4;

    hipMemsetAsync(dis,    0, (size_t)NN * 4, stream);
    hipMemsetAsync(xa,     0, (size_t)NN * 2 * 4, stream);
    hipMemsetAsync(pooled, 0, (size_t)NG * 128 * 4, stream);

    k_deg<<<(NE + 255) / 256, 256, 0, stream>>>(ei + NE, dis);
    k_countsb<<<(NG + 255) / 256, 256, 0, stream>>>(batch, counts);
    k_dis<<<(NN + 255) / 256, 256, 0, stream>>>(dis);

    // GCN layer 1: aggregate x first (2 channels), then W1+bias+relu (agg pre-filled)
    k_edgex<<<(NE + 255) / 256, 256, 0, stream>>>(ei, dis, x, xa);
    k_h1<<<(NN * 64 + 255) / 256, 256, 0, stream>>>(x, xa, dis, W1, b1, h1, agg);

    // GCN layer 2: aggregate h1 (64 channels), then fused W2+bias+relu+segment-pool
    k_edgeh<<<(NE * 64 + 255) / 256, 256, 0, stream>>>(ei, dis, h1, agg);
    k_l2pool<<<NN / BN, 256, 0, stream>>>(agg, W2, b2, batch, pooled);

    // fused MLP head
    k_head<<<NG, 256, 0, stream>>>(feat, fW1, fb1, fg1, fbe1, frm1, frv1, fW2, fb2,
                                   uW1, ub1, ug1, ube1, urm1, urv1,
                                   uW2, ub2, ug2, ube2, urm2, urv2, uW3, ub3,
                                   pooled, counts, out);
}

// Round 8
// 301.613 us; speedup vs baseline: 1.7292x; 1.2226x over previous
//
#include <hip/hip_runtime.h>
#include <hip/hip_bf16.h>
#include <math.h>

typedef __hip_bfloat16 bf16;
static __device__ __forceinline__ float b2f(bf16 v) { return __bfloat162float(v); }

constexpr int NN = 200000;   // nodes
constexpr int NE = 600000;   // edges
constexpr int NG = 512;      // graphs
constexpr int KB = 16;       // bucket capacity (Poisson(3): P(deg>16)~1e-7; overflow path below)
constexpr int OVFCAP = 8192;

// ---------------- bucket edges by dst (also produces in-degree in cnt) ----------------
__global__ void k_bucket(const int* __restrict__ ei, int* __restrict__ cnt,
                         int* __restrict__ bkt, int* __restrict__ ovf, int* __restrict__ novf) {
    int e = blockIdx.x * blockDim.x + threadIdx.x;
    if (e >= NE) return;
    int s = ei[e], d = ei[NE + e];
    int slot = atomicAdd(&cnt[d], 1);
    if (slot < KB) bkt[d * KB + slot] = s;
    else { int o = atomicAdd(novf, 1); if (o < OVFCAP) ovf[o] = e; }
}

// counts[g] via binary search on the SORTED batch array (no atomics)
__global__ void k_countsb(const int* __restrict__ batch, float* __restrict__ counts) {
    int g = blockIdx.x * blockDim.x + threadIdx.x;
    if (g >= NG) return;
    int lo = 0, hi = NN;
    while (lo < hi) { int m = (lo + hi) >> 1; if (batch[m] < g) lo = m + 1; else hi = m; }
    int first = lo;
    lo = 0; hi = NN;
    while (lo < hi) { int m = (lo + hi) >> 1; if (batch[m] < g + 1) lo = m + 1; else hi = m; }
    counts[g] = (float)(lo - first);
}

__global__ void k_dis(const int* __restrict__ cnt, float* __restrict__ dis) {
    int n = blockIdx.x * blockDim.x + threadIdx.x;
    if (n < NN) dis[n] = rsqrtf((float)cnt[n] + 1.0f);   // +1 self-loop
}

// ---------------- edge scatter of raw x (2 channels): xa[d] += x[s]*w ----------------
__global__ void k_edgex(const int* __restrict__ ei, const float* __restrict__ dis,
                        const float* __restrict__ x, float* __restrict__ xa) {
    int e = blockIdx.x * blockDim.x + threadIdx.x;
    if (e >= NE) return;
    int s = ei[e], d = ei[NE + e];
    float w = dis[s] * dis[d];
    atomicAdd(&xa[d * 2 + 0], x[s * 2 + 0] * w);
    atomicAdd(&xa[d * 2 + 1], x[s * 2 + 1] * w);
}

// ---------------- layer1 finalize: h1 = relu((xa + x*dis^2)@W1 + b1) -> bf16 ----------------
__global__ void k_h1(const float* __restrict__ x, const float* __restrict__ xa,
                     const float* __restrict__ dis, const float* __restrict__ W1,
                     const float* __restrict__ b1, bf16* __restrict__ h1) {
    int t = blockIdx.x * blockDim.x + threadIdx.x;
    if (t >= NN * 64) return;
    int n = t >> 6, k = t & 63;
    float dd = dis[n]; dd *= dd;
    float a0 = xa[n * 2 + 0] + x[n * 2 + 0] * dd;
    float a1 = xa[n * 2 + 1] + x[n * 2 + 1] * dd;
    float v = fmaxf(a0 * W1[k] + a1 * W1[64 + k] + b1[k], 0.0f);
    h1[t] = __float2bfloat16(v);
}

// ---------------- GATHER aggregation (replaces 154MB-atomic k_edgeh):
// one wave per dst node, lane = channel. Per edge: coalesced 128B h1 row +
// broadcast dis[s]; accumulate in register; single coalesced agg write.
// agg[d][k] = (sum_s h1[s][k]*dis[s] + h1[d][k]*dis[d]) * dis[d]
__global__ __launch_bounds__(256) void k_agg(const int* __restrict__ cnt,
                        const int* __restrict__ bkt, const float* __restrict__ dis,
                        const bf16* __restrict__ h1, float* __restrict__ agg) {
    int d = (blockIdx.x * 256 + threadIdx.x) >> 6;
    if (d >= NN) return;
    int lane = threadIdx.x & 63;
    int deg = cnt[d]; if (deg > KB) deg = KB;
    float dd = dis[d];
    float acc = b2f(h1[(size_t)d * 64 + lane]) * dd;      // self-loop term
    for (int i = 0; i < deg; i++) {
        int s = bkt[d * KB + i];
        acc += b2f(h1[(size_t)s * 64 + lane]) * dis[s];
    }
    agg[(size_t)d * 64 + lane] = acc * dd;
}

// overflow edges (deg > KB, ~never): atomic add on top of k_agg's result
__global__ void k_ovf(const int* __restrict__ novf, const int* __restrict__ ovf,
                      const int* __restrict__ ei, const float* __restrict__ dis,
                      const bf16* __restrict__ h1, float* __restrict__ agg) {
    int n = *novf; if (n > OVFCAP) n = OVFCAP;
    for (int idx = blockIdx.x * blockDim.x + threadIdx.x; idx < n * 64;
         idx += gridDim.x * blockDim.x) {
        int i = idx >> 6, lane = idx & 63;
        int e = ovf[i];
        int s = ei[e], d = ei[NE + e];
        atomicAdd(&agg[(size_t)d * 64 + lane], b2f(h1[(size_t)s * 64 + lane]) * dis[s] * dis[d]);
    }
}

// ---------------- fused: h2=relu(agg@W2+b2); segment-reduced pool ----------------
constexpr int BN = 64;
__global__ __launch_bounds__(256) void k_l2pool(const float* __restrict__ agg,
                         const float* __restrict__ W2, const float* __restrict__ b2,
                         const int* __restrict__ batch, float* __restrict__ pooled) {
    __shared__ float gs[BN * 64];       // 16 KB
    int tid = threadIdx.x;

    // stage: 64 rows x 64 floats = 1024 float4, 4 per thread, coalesced
    {
        const float4* __restrict__ src = (const float4*)(agg + (size_t)blockIdx.x * BN * 64);
        float4* dst = (float4*)gs;
#pragma unroll
        for (int k = 0; k < 4; k++) dst[tid + k * 256] = src[tid + k * 256];
    }
    __syncthreads();

    int lane = tid & 63;
    int wid = tid >> 6;
    int nb = wid * 16;                       // local node base (wave strip)
    int gnb = blockIdx.x * BN + nb;          // global node base

    float acc0[16], acc1[16];
#pragma unroll
    for (int n = 0; n < 16; n++) { acc0[n] = 0.0f; acc1[n] = 0.0f; }

    for (int j = 0; j < 64; j += 4) {
        float w00 = W2[(j + 0) * 128 + lane], w01 = W2[(j + 0) * 128 + 64 + lane];
        float w10 = W2[(j + 1) * 128 + lane], w11 = W2[(j + 1) * 128 + 64 + lane];
        float w20 = W2[(j + 2) * 128 + lane], w21 = W2[(j + 2) * 128 + 64 + lane];
        float w30 = W2[(j + 3) * 128 + lane], w31 = W2[(j + 3) * 128 + 64 + lane];
#pragma unroll
        for (int n = 0; n < 16; n++) {
            float4 g = *(const float4*)&gs[(nb + n) * 64 + j];   // broadcast b128
            acc0[n] = fmaf(g.x, w00, acc0[n]);
            acc1[n] = fmaf(g.x, w01, acc1[n]);
            acc0[n] = fmaf(g.y, w10, acc0[n]);
            acc1[n] = fmaf(g.y, w11, acc1[n]);
            acc0[n] = fmaf(g.z, w20, acc0[n]);
            acc1[n] = fmaf(g.z, w21, acc1[n]);
            acc0[n] = fmaf(g.w, w30, acc0[n]);
            acc1[n] = fmaf(g.w, w31, acc1[n]);
        }
    }

    float b2c0 = b2[lane], b2c1 = b2[64 + lane];
    int cur = batch[gnb];
    float s0 = 0.0f, s1 = 0.0f;
#pragma unroll
    for (int n = 0; n < 16; n++) {
        int g = batch[gnb + n];              // wave-uniform branch (batch sorted)
        if (g != cur) {
            atomicAdd(&pooled[cur * 128 + lane], s0);
            atomicAdd(&pooled[cur * 128 + 64 + lane], s1);
            s0 = 0.0f; s1 = 0.0f; cur = g;
        }
        s0 += fmaxf(acc0[n] + b2c0, 0.0f);
        s1 += fmaxf(acc1[n] + b2c1, 0.0f);
    }
    atomicAdd(&pooled[cur * 128 + lane], s0);
    atomicAdd(&pooled[cur * 128 + 64 + lane], s1);
}

// ---------------- fused head: feat MLP + fusion MLP + sigmoid, block per graph ----------------
__global__ void k_head(const float* __restrict__ feat,
                       const float* __restrict__ fW1, const float* __restrict__ fb1,
                       const float* __restrict__ fg1, const float* __restrict__ fbe1,
                       const float* __restrict__ frm1, const float* __restrict__ frv1,
                       const float* __restrict__ fW2, const float* __restrict__ fb2,
                       const float* __restrict__ uW1, const float* __restrict__ ub1,
                       const float* __restrict__ ug1, const float* __restrict__ ube1,
                       const float* __restrict__ urm1, const float* __restrict__ urv1,
                       const float* __restrict__ uW2, const float* __restrict__ ub2,
                       const float* __restrict__ ug2, const float* __restrict__ ube2,
                       const float* __restrict__ urm2, const float* __restrict__ urv2,
                       const float* __restrict__ uW3, const float* __restrict__ ub3,
                       const float* __restrict__ pooled, const float* __restrict__ counts,
                       float* __restrict__ out) {
    int g = blockIdx.x;
    int tid = threadIdx.x;
    __shared__ float t1[256], c[256], d1[192], d2[128];

    float f[8];
#pragma unroll
    for (int i = 0; i < 8; i++) f[i] = feat[g * 8 + i];

    // feat MLP layer 1: 8 -> 256, BN, ReLU
    {
        int j = tid;
        float acc = fb1[j];
#pragma unroll
        for (int i = 0; i < 8; i++) acc += f[i] * fW1[i * 256 + j];
        acc = (acc - frm1[j]) * rsqrtf(frv1[j] + 1e-5f) * fg1[j] + fbe1[j];
        t1[j] = fmaxf(acc, 0.0f);
    }
    __syncthreads();

    // feat MLP layer 2 (256->128) into c[128..255]; pooled mean into c[0..127]
    if (tid < 128) {
        float acc = fb2[tid];
        for (int j = 0; j < 256; j++) acc += t1[j] * fW2[j * 128 + tid];
        c[128 + tid] = acc;
    } else {
        int k = tid - 128;
        float cnt = fmaxf(counts[g], 1.0f);
        c[k] = pooled[g * 128 + k] / cnt;
    }
    __syncthreads();

    // fusion layer 1: 256 -> 192, BN, ReLU
    if (tid < 192) {
        float acc = ub1[tid];
        for (int i = 0; i < 256; i++) acc += c[i] * uW1[i * 192 + tid];
        acc = (acc - urm1[tid]) * rsqrtf(urv1[tid] + 1e-5f) * ug1[tid] + ube1[tid];
        d1[tid] = fmaxf(acc, 0.0f);
    }
    __syncthreads();

    // fusion layer 2: 192 -> 128, BN, ReLU
    if (tid < 128) {
        float acc = ub2[tid];
        for (int i = 0; i < 192; i++) acc += d1[i] * uW2[i * 128 + tid];
        acc = (acc - urm2[tid]) * rsqrtf(urv2[tid] + 1e-5f) * ug2[tid] + ube2[tid];
        d2[tid] = fmaxf(acc, 0.0f);
    }
    __syncthreads();

    // fusion layer 3: 128 -> 1, sigmoid
    if (tid == 0) {
        float s = ub3[0];
        for (int i = 0; i < 128; i++) s += d2[i] * uW3[i];
        out[g] = 1.0f / (1.0f + expf(-s));
    }
}

extern "C" void kernel_launch(void* const* d_in, const int* in_sizes, int n_in,
                              void* d_out, int out_size, void* d_ws, size_t ws_size,
                              hipStream_t stream) {
    const float* x    = (const float*)d_in[0];
    const float* feat = (const float*)d_in[1];
    const float* W1   = (const float*)d_in[2];
    const float* b1   = (const float*)d_in[3];
    const float* W2   = (const float*)d_in[4];
    const float* b2   = (const float*)d_in[5];
    const float* fW1  = (const float*)d_in[6];
    const float* fb1  = (const float*)d_in[7];
    const float* fg1  = (const float*)d_in[8];
    const float* fbe1 = (const float*)d_in[9];
    const float* frm1 = (const float*)d_in[10];
    const float* frv1 = (const float*)d_in[11];
    const float* fW2  = (const float*)d_in[12];
    const float* fb2  = (const float*)d_in[13];
    const float* uW1  = (const float*)d_in[14];
    const float* ub1  = (const float*)d_in[15];
    const float* ug1  = (const float*)d_in[16];
    const float* ube1 = (const float*)d_in[17];
    const float* urm1 = (const float*)d_in[18];
    const float* urv1 = (const float*)d_in[19];
    const float* uW2  = (const float*)d_in[20];
    const float* ub2  = (const float*)d_in[21];
    const float* ug2  = (const float*)d_in[22];
    const float* ube2 = (const float*)d_in[23];
    const float* urm2 = (const float*)d_in[24];
    const float* urv2 = (const float*)d_in[25];
    const float* uW3  = (const float*)d_in[26];
    const float* ub3  = (const float*)d_in[27];
    const int* ei    = (const int*)d_in[28];   // [2, E]
    const int* batch = (const int*)d_in[29];   // [N]
    float* out = (float*)d_out;

    // workspace layout — total ~93 MB
    char* p = (char*)d_ws;
    float* dis    = (float*)p; p += (size_t)NN * 4;
    float* xa     = (float*)p; p += (size_t)NN * 2 * 4;
    float* agg    = (float*)p; p += (size_t)NN * 64 * 4;       // gather output (overwritten)
    bf16*  h1     = (bf16*)p;  p += (size_t)NN * 64 * 2;
    float* counts = (float*)p; p += (size_t)NG * 4;
    float* pooled = (float*)p; p += (size_t)NG * 128 * 4;
    int*   cnt    = (int*)p;   p += (size_t)NN * 4;            // in-degree / bucket cursor
    int*   bkt    = (int*)p;   p += (size_t)NN * KB * 4;       // src ids bucketed by dst
    int*   novf   = (int*)p;   p += 4;
    int*   ovf    = (int*)p;   p += (size_t)OVFCAP * 4;

    hipMemsetAsync(cnt,    0, (size_t)NN * 4, stream);
    hipMemsetAsync(novf,   0, 4, stream);
    hipMemsetAsync(xa,     0, (size_t)NN * 2 * 4, stream);
    hipMemsetAsync(pooled, 0, (size_t)NG * 128 * 4, stream);

    k_bucket<<<(NE + 255) / 256, 256, 0, stream>>>(ei, cnt, bkt, ovf, novf);
    k_countsb<<<(NG + 255) / 256, 256, 0, stream>>>(batch, counts);
    k_dis<<<(NN + 255) / 256, 256, 0, stream>>>(cnt, dis);

    // GCN layer 1: aggregate x (2 channels) then W1+bias+relu
    k_edgex<<<(NE + 255) / 256, 256, 0, stream>>>(ei, dis, x, xa);
    k_h1<<<(NN * 64 + 255) / 256, 256, 0, stream>>>(x, xa, dis, W1, b1, h1);

    // GCN layer 2: GATHER aggregation, then fused W2+bias+relu+segment-pool
    k_agg<<<(NN * 64 + 255) / 256, 256, 0, stream>>>(cnt, bkt, dis, h1, agg);
    k_ovf<<<8, 256, 0, stream>>>(novf, ovf, ei, dis, h1, agg);
    k_l2pool<<<NN / BN, 256, 0, stream>>>(agg, W2, b2, batch, pooled);

    // fused MLP head
    k_head<<<NG, 256, 0, stream>>>(feat, fW1, fb1, fg1, fbe1, frm1, frv1, fW2, fb2,
                                   uW1, ub1, ug1, ube1, urm1, urv1,
                                   uW2, ub2, ug2, ube2, urm2, urv2, uW3, ub3,
                                   pooled, counts, out);
}

// Round 9
// 226.038 us; speedup vs baseline: 2.3073x; 1.3343x over previous
//
#include <hip/hip_runtime.h>
#include <hip/hip_bf16.h>
#include <math.h>

typedef __hip_bfloat16 bf16;
static __device__ __forceinline__ float b2f(bf16 v) { return __bfloat162float(v); }

constexpr int NN = 200000;   // nodes
constexpr int NE = 600000;   // edges
constexpr int NG = 512;      // graphs
constexpr int KB = 16;       // bucket capacity (Poisson(3): P(deg>16) tiny; overflow path below)
constexpr int OVFCAP = 8192;

// ---------------- bucket edges by dst (also produces in-degree in cnt) ----------------
__global__ void k_bucket(const int* __restrict__ ei, int* __restrict__ cnt,
                         int* __restrict__ bkt, int* __restrict__ ovf, int* __restrict__ novf) {
    int e = blockIdx.x * blockDim.x + threadIdx.x;
    if (e >= NE) return;
    int s = ei[e], d = ei[NE + e];
    int slot = atomicAdd(&cnt[d], 1);
    if (slot < KB) bkt[d * KB + slot] = s;
    else { int o = atomicAdd(novf, 1); if (o < OVFCAP) ovf[o] = e; }
}

// counts[g] via binary search on the SORTED batch array (no atomics)
__global__ void k_countsb(const int* __restrict__ batch, float* __restrict__ counts) {
    int g = blockIdx.x * blockDim.x + threadIdx.x;
    if (g >= NG) return;
    int lo = 0, hi = NN;
    while (lo < hi) { int m = (lo + hi) >> 1; if (batch[m] < g) lo = m + 1; else hi = m; }
    int first = lo;
    lo = 0; hi = NN;
    while (lo < hi) { int m = (lo + hi) >> 1; if (batch[m] < g + 1) lo = m + 1; else hi = m; }
    counts[g] = (float)(lo - first);
}

__global__ void k_dis(const int* __restrict__ cnt, float* __restrict__ dis) {
    int n = blockIdx.x * blockDim.x + threadIdx.x;
    if (n < NN) dis[n] = rsqrtf((float)cnt[n] + 1.0f);   // +1 self-loop
}

// ---------------- fused GCN layer 1, wave per node (replaces k_edgex + k_h1 + xa):
// lanes 0..deg-1 gather x[s]*dis[s] IN PARALLEL (one edge per lane, from bkt),
// shfl butterfly reduce, then all 64 lanes compute their channel of
// h1 = relu(((sum + x[d]*dis[d]) * dis[d]) @ W1 + b1). No atomics, no xa.
__global__ __launch_bounds__(256) void k_h1g(const int* __restrict__ cnt,
                      const int* __restrict__ bkt, const float* __restrict__ dis,
                      const float* __restrict__ x, const float* __restrict__ W1,
                      const float* __restrict__ b1,
                      const int* __restrict__ novf, const int* __restrict__ ovf,
                      const int* __restrict__ ei, bf16* __restrict__ h1) {
    int d = (blockIdx.x * 256 + threadIdx.x) >> 6;
    if (d >= NN) return;
    int lane = threadIdx.x & 63;
    int deg = cnt[d];
    int degc = deg < KB ? deg : KB;

    float p0 = 0.0f, p1 = 0.0f;
    if (lane < degc) {
        int s = bkt[d * KB + lane];
        float ws = dis[s];
        float2 xs = ((const float2*)x)[s];
        p0 = xs.x * ws; p1 = xs.y * ws;
    }
    if (deg > KB) {                       // rare overflow: scan tiny ovf list
        int nov = *novf; if (nov > OVFCAP) nov = OVFCAP;
        for (int o = lane; o < nov; o += 64) {
            int e = ovf[o];
            if (ei[NE + e] == d) {
                int s = ei[e];
                float ws = dis[s];
                float2 xs = ((const float2*)x)[s];
                p0 += xs.x * ws; p1 += xs.y * ws;
            }
        }
    }
    // butterfly over 16 lanes (bucket occupies lanes 0-15; ovf adds are strided, reduce all 64)
#pragma unroll
    for (int m = 1; m < 64; m <<= 1) {
        p0 += __shfl_xor(p0, m, 64);
        p1 += __shfl_xor(p1, m, 64);
    }

    float wd = dis[d];
    float2 xd = ((const float2*)x)[d];
    float a0 = (p0 + xd.x * wd) * wd;
    float a1 = (p1 + xd.y * wd) * wd;
    float v = fmaxf(a0 * W1[lane] + a1 * W1[64 + lane] + b1[lane], 0.0f);
    h1[(size_t)d * 64 + lane] = __float2bfloat16(v);
}

// ---------------- GATHER aggregation, wave per dst node, ILP-4 edge loop:
// 4 independent bkt loads + 4 independent h1-row loads in flight per iter
// (runtime-trip serial chain was the round-8 latency bound).
// agg[d][k] = (sum_s h1[s][k]*dis[s] + h1[d][k]*dis[d]) * dis[d]
__global__ __launch_bounds__(256) void k_agg(const int* __restrict__ cnt,
                        const int* __restrict__ bkt, const float* __restrict__ dis,
                        const bf16* __restrict__ h1, float* __restrict__ agg) {
    int d = (blockIdx.x * 256 + threadIdx.x) >> 6;
    if (d >= NN) return;
    int lane = threadIdx.x & 63;
    int deg = cnt[d]; if (deg > KB) deg = KB;
    float dd = dis[d];
    float acc = b2f(h1[(size_t)d * 64 + lane]) * dd;      // self-loop term
    int base = d * KB;
    for (int i = 0; i < deg; i += 4) {
        int c = deg - 1;
        int i1 = i + 1 < c ? i + 1 : c;
        int i2 = i + 2 < c ? i + 2 : c;
        int i3 = i + 3 < c ? i + 3 : c;
        int s0 = bkt[base + i], s1 = bkt[base + i1];
        int s2 = bkt[base + i2], s3 = bkt[base + i3];
        float v0 = b2f(h1[(size_t)s0 * 64 + lane]) * dis[s0];
        float v1 = b2f(h1[(size_t)s1 * 64 + lane]) * dis[s1];
        float v2 = b2f(h1[(size_t)s2 * 64 + lane]) * dis[s2];
        float v3 = b2f(h1[(size_t)s3 * 64 + lane]) * dis[s3];
        acc += v0;
        if (i + 1 < deg) acc += v1;
        if (i + 2 < deg) acc += v2;
        if (i + 3 < deg) acc += v3;
    }
    agg[(size_t)d * 64 + lane] = acc * dd;
}

// overflow edges (deg > KB, ~never): atomic add on top of k_agg's result
__global__ void k_ovf(const int* __restrict__ novf, const int* __restrict__ ovf,
                      const int* __restrict__ ei, const float* __restrict__ dis,
                      const bf16* __restrict__ h1, float* __restrict__ agg) {
    int n = *novf; if (n > OVFCAP) n = OVFCAP;
    for (int idx = blockIdx.x * blockDim.x + threadIdx.x; idx < n * 64;
         idx += gridDim.x * blockDim.x) {
        int i = idx >> 6, lane = idx & 63;
        int e = ovf[i];
        int s = ei[e], d = ei[NE + e];
        atomicAdd(&agg[(size_t)d * 64 + lane], b2f(h1[(size_t)s * 64 + lane]) * dis[s] * dis[d]);
    }
}

// ---------------- fused: h2=relu(agg@W2+b2); segment-reduced pool ----------------
constexpr int BN = 64;
__global__ __launch_bounds__(256) void k_l2pool(const float* __restrict__ agg,
                         const float* __restrict__ W2, const float* __restrict__ b2,
                         const int* __restrict__ batch, float* __restrict__ pooled) {
    __shared__ float gs[BN * 64];       // 16 KB
    int tid = threadIdx.x;

    // stage: 64 rows x 64 floats = 1024 float4, 4 per thread, coalesced
    {
        const float4* __restrict__ src = (const float4*)(agg + (size_t)blockIdx.x * BN * 64);
        float4* dst = (float4*)gs;
#pragma unroll
        for (int k = 0; k < 4; k++) dst[tid + k * 256] = src[tid + k * 256];
    }
    __syncthreads();

    int lane = tid & 63;
    int wid = tid >> 6;
    int nb = wid * 16;                       // local node base (wave strip)
    int gnb = blockIdx.x * BN + nb;          // global node base

    float acc0[16], acc1[16];
#pragma unroll
    for (int n = 0; n < 16; n++) { acc0[n] = 0.0f; acc1[n] = 0.0f; }

    for (int j = 0; j < 64; j += 4) {
        float w00 = W2[(j + 0) * 128 + lane], w01 = W2[(j + 0) * 128 + 64 + lane];
        float w10 = W2[(j + 1) * 128 + lane], w11 = W2[(j + 1) * 128 + 64 + lane];
        float w20 = W2[(j + 2) * 128 + lane], w21 = W2[(j + 2) * 128 + 64 + lane];
        float w30 = W2[(j + 3) * 128 + lane], w31 = W2[(j + 3) * 128 + 64 + lane];
#pragma unroll
        for (int n = 0; n < 16; n++) {
            float4 g = *(const float4*)&gs[(nb + n) * 64 + j];   // broadcast b128
            acc0[n] = fmaf(g.x, w00, acc0[n]);
            acc1[n] = fmaf(g.x, w01, acc1[n]);
            acc0[n] = fmaf(g.y, w10, acc0[n]);
            acc1[n] = fmaf(g.y, w11, acc1[n]);
            acc0[n] = fmaf(g.z, w20, acc0[n]);
            acc1[n] = fmaf(g.z, w21, acc1[n]);
            acc0[n] = fmaf(g.w, w30, acc0[n]);
            acc1[n] = fmaf(g.w, w31, acc1[n]);
        }
    }

    float b2c0 = b2[lane], b2c1 = b2[64 + lane];
    int cur = batch[gnb];
    float s0 = 0.0f, s1 = 0.0f;
#pragma unroll
    for (int n = 0; n < 16; n++) {
        int g = batch[gnb + n];              // wave-uniform branch (batch sorted)
        if (g != cur) {
            atomicAdd(&pooled[cur * 128 + lane], s0);
            atomicAdd(&pooled[cur * 128 + 64 + lane], s1);
            s0 = 0.0f; s1 = 0.0f; cur = g;
        }
        s0 += fmaxf(acc0[n] + b2c0, 0.0f);
        s1 += fmaxf(acc1[n] + b2c1, 0.0f);
    }
    atomicAdd(&pooled[cur * 128 + lane], s0);
    atomicAdd(&pooled[cur * 128 + 64 + lane], s1);
}

// ---------------- fused head: feat MLP + fusion MLP + sigmoid, block per graph ----------------
__global__ void k_head(const float* __restrict__ feat,
                       const float* __restrict__ fW1, const float* __restrict__ fb1,
                       const float* __restrict__ fg1, const float* __restrict__ fbe1,
                       const float* __restrict__ frm1, const float* __restrict__ frv1,
                       const float* __restrict__ fW2, const float* __restrict__ fb2,
                       const float* __restrict__ uW1, const float* __restrict__ ub1,
                       const float* __restrict__ ug1, const float* __restrict__ ube1,
                       const float* __restrict__ urm1, const float* __restrict__ urv1,
                       const float* __restrict__ uW2, const float* __restrict__ ub2,
                       const float* __restrict__ ug2, const float* __restrict__ ube2,
                       const float* __restrict__ urm2, const float* __restrict__ urv2,
                       const float* __restrict__ uW3, const float* __restrict__ ub3,
                       const float* __restrict__ pooled, const float* __restrict__ counts,
                       float* __restrict__ out) {
    int g = blockIdx.x;
    int tid = threadIdx.x;
    __shared__ float t1[256], c[256], d1[192], d2[128];

    float f[8];
#pragma unroll
    for (int i = 0; i < 8; i++) f[i] = feat[g * 8 + i];

    // feat MLP layer 1: 8 -> 256, BN, ReLU
    {
        int j = tid;
        float acc = fb1[j];
#pragma unroll
        for (int i = 0; i < 8; i++) acc += f[i] * fW1[i * 256 + j];
        acc = (acc - frm1[j]) * rsqrtf(frv1[j] + 1e-5f) * fg1[j] + fbe1[j];
        t1[j] = fmaxf(acc, 0.0f);
    }
    __syncthreads();

    // feat MLP layer 2 (256->128) into c[128..255]; pooled mean into c[0..127]
    if (tid < 128) {
        float acc = fb2[tid];
        for (int j = 0; j < 256; j++) acc += t1[j] * fW2[j * 128 + tid];
        c[128 + tid] = acc;
    } else {
        int k = tid - 128;
        float cnt = fmaxf(counts[g], 1.0f);
        c[k] = pooled[g * 128 + k] / cnt;
    }
    __syncthreads();

    // fusion layer 1: 256 -> 192, BN, ReLU
    if (tid < 192) {
        float acc = ub1[tid];
        for (int i = 0; i < 256; i++) acc += c[i] * uW1[i * 192 + tid];
        acc = (acc - urm1[tid]) * rsqrtf(urv1[tid] + 1e-5f) * ug1[tid] + ube1[tid];
        d1[tid] = fmaxf(acc, 0.0f);
    }
    __syncthreads();

    // fusion layer 2: 192 -> 128, BN, ReLU
    if (tid < 128) {
        float acc = ub2[tid];
        for (int i = 0; i < 192; i++) acc += d1[i] * uW2[i * 128 + tid];
        acc = (acc - urm2[tid]) * rsqrtf(urv2[tid] + 1e-5f) * ug2[tid] + ube2[tid];
        d2[tid] = fmaxf(acc, 0.0f);
    }
    __syncthreads();

    // fusion layer 3: 128 -> 1, sigmoid
    if (tid == 0) {
        float s = ub3[0];
        for (int i = 0; i < 128; i++) s += d2[i] * uW3[i];
        out[g] = 1.0f / (1.0f + expf(-s));
    }
}

extern "C" void kernel_launch(void* const* d_in, const int* in_sizes, int n_in,
                              void* d_out, int out_size, void* d_ws, size_t ws_size,
                              hipStream_t stream) {
    const float* x    = (const float*)d_in[0];
    const float* feat = (const float*)d_in[1];
    const float* W1   = (const float*)d_in[2];
    const float* b1   = (const float*)d_in[3];
    const float* W2   = (const float*)d_in[4];
    const float* b2   = (const float*)d_in[5];
    const float* fW1  = (const float*)d_in[6];
    const float* fb1  = (const float*)d_in[7];
    const float* fg1  = (const float*)d_in[8];
    const float* fbe1 = (const float*)d_in[9];
    const float* frm1 = (const float*)d_in[10];
    const float* frv1 = (const float*)d_in[11];
    const float* fW2  = (const float*)d_in[12];
    const float* fb2  = (const float*)d_in[13];
    const float* uW1  = (const float*)d_in[14];
    const float* ub1  = (const float*)d_in[15];
    const float* ug1  = (const float*)d_in[16];
    const float* ube1 = (const float*)d_in[17];
    const float* urm1 = (const float*)d_in[18];
    const float* urv1 = (const float*)d_in[19];
    const float* uW2  = (const float*)d_in[20];
    const float* ub2  = (const float*)d_in[21];
    const float* ug2  = (const float*)d_in[22];
    const float* ube2 = (const float*)d_in[23];
    const float* urm2 = (const float*)d_in[24];
    const float* urv2 = (const float*)d_in[25];
    const float* uW3  = (const float*)d_in[26];
    const float* ub3  = (const float*)d_in[27];
    const int* ei    = (const int*)d_in[28];   // [2, E]
    const int* batch = (const int*)d_in[29];   // [N]
    float* out = (float*)d_out;

    // workspace layout — total ~92 MB
    char* p = (char*)d_ws;
    float* dis    = (float*)p; p += (size_t)NN * 4;
    float* agg    = (float*)p; p += (size_t)NN * 64 * 4;       // gather output
    bf16*  h1     = (bf16*)p;  p += (size_t)NN * 64 * 2;
    float* counts = (float*)p; p += (size_t)NG * 4;
    float* pooled = (float*)p; p += (size_t)NG * 128 * 4;
    int*   cnt    = (int*)p;   p += (size_t)NN * 4;            // in-degree / bucket cursor
    int*   bkt    = (int*)p;   p += (size_t)NN * KB * 4;       // src ids bucketed by dst
    int*   novf   = (int*)p;   p += 4;
    int*   ovf    = (int*)p;   p += (size_t)OVFCAP * 4;

    hipMemsetAsync(cnt,    0, (size_t)NN * 4, stream);
    hipMemsetAsync(novf,   0, 4, stream);
    hipMemsetAsync(pooled, 0, (size_t)NG * 128 * 4, stream);

    k_bucket<<<(NE + 255) / 256, 256, 0, stream>>>(ei, cnt, bkt, ovf, novf);
    k_countsb<<<(NG + 255) / 256, 256, 0, stream>>>(batch, counts);
    k_dis<<<(NN + 255) / 256, 256, 0, stream>>>(cnt, dis);

    // GCN layer 1: fused parallel-gather + W1 + bias + relu (wave per node)
    k_h1g<<<(NN * 64 + 255) / 256, 256, 0, stream>>>(cnt, bkt, dis, x, W1, b1,
                                                     novf, ovf, ei, h1);

    // GCN layer 2: ILP-4 gather aggregation, then fused W2+bias+relu+segment-pool
    k_agg<<<(NN * 64 + 255) / 256, 256, 0, stream>>>(cnt, bkt, dis, h1, agg);
    k_ovf<<<8, 256, 0, stream>>>(novf, ovf, ei, dis, h1, agg);
    k_l2pool<<<NN / BN, 256, 0, stream>>>(agg, W2, b2, batch, pooled);

    // fused MLP head
    k_head<<<NG, 256, 0, stream>>>(feat, fW1, fb1, fg1, fbe1, frm1, frv1, fW2, fb2,
                                   uW1, ub1, ug1, ube1, urm1, urv1,
                                   uW2, ub2, ug2, ube2, urm2, urv2, uW3, ub3,
                                   pooled, counts, out);
}